// Round 3
// baseline (393.193 us; speedup 1.0000x reference)
//
#include <hip/hip_runtime.h>
#include <hip/hip_bf16.h>
#include <math.h>

#define BB 16
#define NN 512
#define DD 256
#define KK 12

typedef __bf16 bf16x8 __attribute__((ext_vector_type(8)));
typedef __bf16 bf16x4 __attribute__((ext_vector_type(4)));
typedef float  f32x4  __attribute__((ext_vector_type(4)));

// workspace layout (bytes)
#define WS_WM     0              // wm[b,n] = w*mask_n, f32, 32KB
#define WS_NCNT   32768          // ncnt[b,m] int32 neighbor counts (atomic), 32KB
#define WS_NODEBF 65536          // node bf16 [B][N][D] (unscaled, for self term), 4MB
#define WS_NODET  4259840        // node_t bf16 [B][D][N], scaled by wm, 4MB
#define WS_WKBF   8454144        // Wk bf16 [K][D][D], 1.5MB
#define WS_WSBF   10027008       // Ws bf16 [D][D], 128KB
#define WS_T      10158080       // T bf16 [B][N][K][D]  (b,m,k,e), 50MB

// ---------------------------------------------------------------- k1: w, all_weight, wm, node_bf16
__global__ __launch_bounds__(256) void k1_prep(const float* __restrict__ node,
        const float* __restrict__ Ww, const float* __restrict__ bw,
        const int* __restrict__ node_mask,
        float* __restrict__ wm, __bf16* __restrict__ node_bf,
        float* __restrict__ all_w) {
    int t = threadIdx.x;
    int lane = t & 63;
    int row = blockIdx.x * 4 + (t >> 6);           // b*N + n
    const float4 nv = *(const float4*)(node + (size_t)row * DD + lane * 4);
    const float4 wv = *(const float4*)(Ww + lane * 4);
    float dot = nv.x*wv.x + nv.y*wv.y + nv.z*wv.z + nv.w*wv.w;
    #pragma unroll
    for (int off = 32; off > 0; off >>= 1) dot += __shfl_xor(dot, off);
    float w = 1.0f / (1.0f + expf(-(dot + bw[0])));
    int mk = node_mask[row];
    if (lane == 0) {
        wm[row]    = w * (float)mk;
        all_w[row] = w;
    }
    bf16x4 nb = {(__bf16)nv.x, (__bf16)nv.y, (__bf16)nv.z, (__bf16)nv.w};
    *(bf16x4*)(node_bf + (size_t)row * DD + lane * 4) = nb;
}

// ---------------------------------------------------------------- k1b: Wk, Ws -> bf16
__global__ __launch_bounds__(256) void k1b_convert(const float* __restrict__ Wk,
        const float* __restrict__ Ws, __bf16* __restrict__ Wk_bf, __bf16* __restrict__ Ws_bf) {
    const int KDD = KK * DD * DD;
    int idx = (blockIdx.x * 256 + threadIdx.x) * 4;
    if (idx < KDD) {
        float4 v = *(const float4*)(Wk + idx);
        bf16x4 o = {(__bf16)v.x, (__bf16)v.y, (__bf16)v.z, (__bf16)v.w};
        *(bf16x4*)(Wk_bf + idx) = o;
    } else {
        int j = idx - KDD;
        if (j < DD * DD) {
            float4 v = *(const float4*)(Ws + j);
            bf16x4 o = {(__bf16)v.x, (__bf16)v.y, (__bf16)v.z, (__bf16)v.w};
            *(bf16x4*)(Ws_bf + j) = o;
        }
    }
}

// ---------------------------------------------------------------- k2: node fp32 [B][N][D] -> node_t bf16 [B][D][N] scaled by wm[b,n]
__global__ __launch_bounds__(256) void k2_transpose(const float* __restrict__ node,
        const float* __restrict__ wm, __bf16* __restrict__ dst) {
    __shared__ float tile[64][65];
    int bx = blockIdx.x;
    int b = bx >> 5; int rest = bx & 31; int nt = rest >> 2; int dt = rest & 3;
    int n0 = nt * 64, d0 = dt * 64;
    int t = threadIdx.x;
    #pragma unroll
    for (int i = 0; i < 16; i++) {
        int idx = i * 256 + t;
        int n = idx >> 6, d = idx & 63;
        tile[n][d] = node[((size_t)(b * NN + n0 + n)) * DD + d0 + d];
    }
    __syncthreads();
    #pragma unroll
    for (int i = 0; i < 16; i++) {
        int idx = i * 256 + t;
        int d = idx >> 6, n = idx & 63;
        float w = wm[b * NN + n0 + n];
        dst[((size_t)(b * DD + d0 + d)) * NN + n0 + n] = (__bf16)(tile[n][d] * w);
    }
}

// ---------------------------------------------------------------- k4: T[b,m,k,e] = sum_n g[m,n](n!=m) * wnode_t[b,e,n]
//  A = raw adjacency bits -> bf16 via pack trick; counts fused; B frags direct from global.
__global__ __launch_bounds__(256) void k4_stageA(const int* __restrict__ graphs,
        const int* __restrict__ node_mask, const __bf16* __restrict__ node_t,
        __bf16* __restrict__ T, int* __restrict__ ncnt) {
    __shared__ __align__(16) __bf16 Asub[64][72];
    int bx = blockIdx.x;
    int mt = bx & 7;
    int kb = bx >> 3;
    int b = kb & 15;
    int k = kb >> 4;
    int m0 = mt * 64;
    int t = threadIdx.x;
    int lane = t & 63;
    int wave = t >> 6;
    int q = lane >> 4;
    int l16 = lane & 15;
    int e0 = wave * 64;                // wave's e-subrange (output cols)

    f32x4 acc[4][4];
    #pragma unroll
    for (int i = 0; i < 4; i++)
        #pragma unroll
        for (int j = 0; j < 4; j++) acc[i][j] = (f32x4){0.f, 0.f, 0.f, 0.f};

    int am = t >> 2;                   // A row 0..63 (wave w builds rows w*16..w*16+16)
    int aq = t & 3;                    // 16-col chunk
    const int* grow = graphs + ((size_t)((k * BB + b) * NN + m0 + am)) * NN;
    const int* mrow = node_mask + b * NN;
    int mg = m0 + am;                  // global row (diagonal)
    unsigned cnt = 0;                  // packed 16-bit pair accumulator

    for (int n0 = 0; n0 < NN; n0 += 64) {
        // ---- A tile build: g -> bf16 {0,1}, diag cleared, count fused
        #pragma unroll
        for (int i = 0; i < 4; i++) {
            int nbase = n0 + aq * 16 + i * 4;
            int4 g  = *(const int4*)(grow + nbase);
            int4 mk = *(const int4*)(mrow + nbase);
            unsigned p0 = (unsigned)g.x | ((unsigned)g.y << 16);
            unsigned p1 = (unsigned)g.z | ((unsigned)g.w << 16);
            unsigned drel = (unsigned)(mg - nbase);
            if (drel < 4u) {           // clear diagonal bit (rare, one (i,n0) per thread)
                unsigned bit = 1u << (16 * (drel & 1));
                if (drel < 2u) p0 &= ~bit; else p1 &= ~bit;
            }
            unsigned mp0 = (unsigned)mk.x | ((unsigned)mk.y << 16);
            unsigned mp1 = (unsigned)mk.z | ((unsigned)mk.w << 16);
            cnt += (p0 & mp0) + (p1 & mp1);
            uint2 st;
            st.x = p0 * 0x3F80u;       // two bf16 {0.0,1.0} at once
            st.y = p1 * 0x3F80u;
            *(uint2*)&Asub[am][aq * 16 + i * 4] = st;
        }
        __syncthreads();
        // ---- MFMA: A frags from LDS, B frags straight from global (L2-hot node_t)
        #pragma unroll
        for (int kk = 0; kk < 2; kk++) {
            bf16x8 af[4], bfr[4];
            #pragma unroll
            for (int fm = 0; fm < 4; fm++)
                af[fm] = *(const bf16x8*)&Asub[fm * 16 + l16][kk * 32 + q * 8];
            #pragma unroll
            for (int fd = 0; fd < 4; fd++)
                bfr[fd] = *(const bf16x8*)(node_t +
                    ((size_t)(b * DD + e0 + fd * 16 + l16)) * NN + n0 + kk * 32 + q * 8);
            #pragma unroll
            for (int fm = 0; fm < 4; fm++)
                #pragma unroll
                for (int fd = 0; fd < 4; fd++)
                    acc[fm][fd] = __builtin_amdgcn_mfma_f32_16x16x32_bf16(
                        af[fm], bfr[fd], acc[fm][fd], 0, 0, 0);
        }
        __syncthreads();
    }

    // ---- neighbor count: unpack halves, reduce over the 4 aq lanes, one atomic per row
    cnt = (cnt & 0xFFFFu) + (cnt >> 16);
    int ci = (int)cnt;
    ci += __shfl_xor(ci, 1);
    ci += __shfl_xor(ci, 2);
    if (aq == 0) atomicAdd(&ncnt[b * NN + mg], ci);

    // ---- store T bf16 in [b][m][k][e]. C/D: col=lane&15, row=(lane>>4)*4+reg
    #pragma unroll
    for (int fm = 0; fm < 4; fm++)
        #pragma unroll
        for (int fd = 0; fd < 4; fd++) {
            int col = e0 + fd * 16 + l16;
            #pragma unroll
            for (int r = 0; r < 4; r++) {
                int m = m0 + fm * 16 + q * 4 + r;
                T[((size_t)((b * NN + m) * KK + k)) * DD + col] = (__bf16)acc[fm][fd][r];
            }
        }
}

// ---------------------------------------------------------------- k5: LDS-free register GEMM
// out[b,m,d] = relu( s[b,m] * sum_{k,e} T[b,m,k,e] Wk[k,d,e]  +  sum_e node[b,m,e] Ws[d,e] + bs[d] )
// 64x64 out tile; 4 waves split the reduction dim (each an e-subrange of 64), full-tile partials,
// deterministic phased LDS reduction at the end.
__global__ __launch_bounds__(256) void k5_stageB(const __bf16* __restrict__ T,
        const __bf16* __restrict__ Wk_bf, const __bf16* __restrict__ node_bf,
        const __bf16* __restrict__ Ws_bf, const float* __restrict__ bs,
        const int* __restrict__ ncnt, const int* __restrict__ node_mask,
        float* __restrict__ out) {
    __shared__ float redbuf[64][65];
    int bx = blockIdx.x;
    int b = bx >> 5; int rest = bx & 31; int mt = rest >> 2; int dt = rest & 3;
    int m0 = mt * 64, d0 = dt * 64;
    int t = threadIdx.x;
    int lane = t & 63;
    int wave = t >> 6;
    int q = lane >> 4;
    int l16 = lane & 15;
    int ew = wave * 64;                // wave's e-subrange

    f32x4 acc[4][4];
    #pragma unroll
    for (int i = 0; i < 4; i++)
        #pragma unroll
        for (int j = 0; j < 4; j++) acc[i][j] = (f32x4){0.f, 0.f, 0.f, 0.f};

    // 12 agg rounds, no barriers, frags direct from L2/L3
    for (int k = 0; k < KK; k++) {
        #pragma unroll
        for (int kk = 0; kk < 2; kk++) {
            int eoff = ew + kk * 32 + q * 8;
            bf16x8 af[4], bfr[4];
            #pragma unroll
            for (int fm = 0; fm < 4; fm++)
                af[fm] = *(const bf16x8*)(T +
                    ((size_t)(b * NN + m0 + fm * 16 + l16)) * (KK * DD) + k * DD + eoff);
            #pragma unroll
            for (int fd = 0; fd < 4; fd++)
                bfr[fd] = *(const bf16x8*)(Wk_bf +
                    ((size_t)(k * DD + d0 + fd * 16 + l16)) * DD + eoff);
            #pragma unroll
            for (int fm = 0; fm < 4; fm++)
                #pragma unroll
                for (int fd = 0; fd < 4; fd++)
                    acc[fm][fd] = __builtin_amdgcn_mfma_f32_16x16x32_bf16(
                        af[fm], bfr[fd], acc[fm][fd], 0, 0, 0);
        }
    }

    // scale agg partial by s[b,m] (linear => per-wave partial scaling is exact)
    #pragma unroll
    for (int fm = 0; fm < 4; fm++) {
        #pragma unroll
        for (int r = 0; r < 4; r++) {
            int m = m0 + fm * 16 + q * 4 + r;
            int c = ncnt[b * NN + m];
            float s = (float)node_mask[b * NN + m] / (float)(c >= 1 ? c : 1);
            #pragma unroll
            for (int fd = 0; fd < 4; fd++) acc[fm][fd][r] *= s;
        }
    }

    // self round: + node @ Ws^T
    #pragma unroll
    for (int kk = 0; kk < 2; kk++) {
        int eoff = ew + kk * 32 + q * 8;
        bf16x8 af[4], bfr[4];
        #pragma unroll
        for (int fm = 0; fm < 4; fm++)
            af[fm] = *(const bf16x8*)(node_bf +
                ((size_t)(b * NN + m0 + fm * 16 + l16)) * DD + eoff);
        #pragma unroll
        for (int fd = 0; fd < 4; fd++)
            bfr[fd] = *(const bf16x8*)(Ws_bf +
                ((size_t)(d0 + fd * 16 + l16)) * DD + eoff);
        #pragma unroll
        for (int fm = 0; fm < 4; fm++)
            #pragma unroll
            for (int fd = 0; fd < 4; fd++)
                acc[fm][fd] = __builtin_amdgcn_mfma_f32_16x16x32_bf16(
                    af[fm], bfr[fd], acc[fm][fd], 0, 0, 0);
    }

    // deterministic phased cross-wave reduction
    for (int w = 0; w < 4; w++) {
        if (wave == w) {
            #pragma unroll
            for (int fm = 0; fm < 4; fm++)
                #pragma unroll
                for (int fd = 0; fd < 4; fd++) {
                    int dd2 = fd * 16 + l16;
                    #pragma unroll
                    for (int r = 0; r < 4; r++) {
                        int mm = fm * 16 + q * 4 + r;
                        if (w == 0) redbuf[mm][dd2] = acc[fm][fd][r];
                        else        redbuf[mm][dd2] += acc[fm][fd][r];
                    }
                }
        }
        __syncthreads();
    }

    // epilogue: + bs, relu, float4 stores
    int row = t >> 2;
    int c0 = (t & 3) * 16;
    #pragma unroll
    for (int j = 0; j < 4; j++) {
        int d = d0 + c0 + j * 4;
        float4 bv = *(const float4*)(bs + d);
        float4 v;
        v.x = fmaxf(redbuf[row][c0 + j * 4 + 0] + bv.x, 0.0f);
        v.y = fmaxf(redbuf[row][c0 + j * 4 + 1] + bv.y, 0.0f);
        v.z = fmaxf(redbuf[row][c0 + j * 4 + 2] + bv.z, 0.0f);
        v.w = fmaxf(redbuf[row][c0 + j * 4 + 3] + bv.w, 0.0f);
        *(float4*)(out + ((size_t)(b * NN + m0 + row)) * DD + d) = v;
    }
}

// ----------------------------------------------------------------
extern "C" void kernel_launch(void* const* d_in, const int* in_sizes, int n_in,
                              void* d_out, int out_size, void* d_ws, size_t ws_size,
                              hipStream_t stream) {
    const float* node      = (const float*)d_in[0];
    const float* Ww        = (const float*)d_in[1];
    const float* bw        = (const float*)d_in[2];
    const float* Ws        = (const float*)d_in[3];
    const float* bs        = (const float*)d_in[4];
    const float* Wk        = (const float*)d_in[5];
    const int*   node_mask = (const int*)d_in[6];
    const int*   graphs    = (const int*)d_in[7];
    float* out   = (float*)d_out;
    float* all_w = out + (size_t)BB * NN * DD;

    char* ws = (char*)d_ws;
    float*  wm      = (float*)(ws + WS_WM);
    int*    ncnt    = (int*)(ws + WS_NCNT);
    __bf16* node_bf = (__bf16*)(ws + WS_NODEBF);
    __bf16* node_t  = (__bf16*)(ws + WS_NODET);
    __bf16* Wk_bf   = (__bf16*)(ws + WS_WKBF);
    __bf16* Ws_bf   = (__bf16*)(ws + WS_WSBF);
    __bf16* Tbuf    = (__bf16*)(ws + WS_T);

    hipMemsetAsync(ncnt, 0, BB * NN * sizeof(int), stream);
    k1_prep    <<<2048, 256, 0, stream>>>(node, Ww, bw, node_mask, wm, node_bf, all_w);
    k1b_convert<<< 832, 256, 0, stream>>>(Wk, Ws, Wk_bf, Ws_bf);
    k2_transpose<<<512, 256, 0, stream>>>(node, wm, node_t);
    k4_stageA  <<<1536, 256, 0, stream>>>(graphs, node_mask, node_t, Tbuf, ncnt);
    k5_stageB  <<< 512, 256, 0, stream>>>(Tbuf, Wk_bf, node_bf, Ws_bf, bs, ncnt, node_mask, out);
}